// Round 19
// baseline (74.389 us; speedup 1.0000x reference)
//
#include <hip/hip_runtime.h>
#include <math.h>

// NSVQ: N=131072 rows, D=64, K=1024 codes (fp32).
// out (flat f32): [0,N*D) quantized; [N*D] perplexity; [N*D+1,+K) counts.
// ws layout:
//   [0,4096)         cn2k   f32[K]     2048*(||c||^2 + 512)
//   [4096,8192)      counts int[K]
//   [8192,532480)    best   uint[N]    bit31=flag, bits10..19=k2, bits0..9=k1
//   [532480,663552)  cbf    fp16[K*64] codebook, MFMA-fragment order
// fragment order: entry (16B) index = ct*128 + kk*64 + lg*16 + l15
//   holds code (ct*16+l15), dims [kk*32+lg*8, +8)  -> wave load is coalesced 1KB

#define NSVQ_D 64
#define ABN 128      // rows per argmin block (256 thr, 4 waves x 32 rows -> grid 1024, 4 blk/CU)
#define THR_Q 12u    // flag threshold in packed quanta (worst quantum 0.03125 raw @ e=19)
                     // certifies gap >= 0.375 raw > 2*fp16_err(0.12) + quantum

typedef __attribute__((ext_vector_type(8))) _Float16 half8;
typedef __attribute__((ext_vector_type(4))) float f32x4;

// ---------------- prep: codebook norms + fp16 fragment-order plane + zero counts ----------------
__global__ __launch_bounds__(256)
void nsvq_prep(const float* __restrict__ cb,
               ushort* __restrict__ cbf,
               float* __restrict__ cn2k, int* __restrict__ counts, int K) {
  if (blockIdx.x == 0) ((int4*)counts)[threadIdx.x] = make_int4(0, 0, 0, 0);
  int r = blockIdx.x * 256 + threadIdx.x;  // one code per thread
  if (r >= K) return;
  const float* row = cb + (long)r * NSVQ_D;
  float nrm = 0.f;
#pragma unroll
  for (int j = 0; j < 8; ++j) {            // dim block j = dims 8j..8j+7
    float4 v0 = *(const float4*)(row + j * 8);
    float4 v1 = *(const float4*)(row + j * 8 + 4);
    float f[8] = {v0.x, v0.y, v0.z, v0.w, v1.x, v1.y, v1.z, v1.w};
    half8 hv;
#pragma unroll
    for (int e = 0; e < 8; ++e) {
      nrm = fmaf(f[e], f[e], nrm);
      hv[e] = (_Float16)f[e];
    }
    // fragment-order entry: ct*128 + kk*64 + lg*16 + l15
    int blk = (r >> 4) * 128 + (j >> 2) * 64 + (j & 3) * 16 + (r & 15);
    *(half8*)(cbf + blk * 8) = hv;
  }
  cn2k[r] = 2048.f * (nrm + 512.f);        // acc-init constant; scores in (0.78M, 1.72M)
}

// ---------------- MFMA argmin: fp16, 4 waves x 32 rows, per-block ct-stagger ----------------
// Stagger rationale: without it every wave chip-wide reads the SAME 2KB slice of the
// 128KB codebook each step -> L2 bank hotspot serializes all CUs (R16/R17: occupancy
// and pipeline depth both null). ct0 spreads blocks across the 64 slices.
__global__ __launch_bounds__(256, 4)
void nsvq_argmin_mfma(const float* __restrict__ x,
                      const ushort* __restrict__ cbf,
                      const float* __restrict__ cn2k,
                      uint* __restrict__ best) {
  const int tid = threadIdx.x;
  const int lane = tid & 63;
  const int wid = tid >> 6;                // 0..3, each wave owns 32 rows
  const int l15 = lane & 15;
  const int lg = lane >> 4;                // 0..3
  const long brow = (long)blockIdx.x * ABN;
  const int wrow = wid * 32;
  // per-block phase: consecutive CUs differ by 1 slice; same-CU blocks (b, b+256, ...)
  // differ by 16 slices -> maximal spread of L2 traffic across the codebook
  const int ct0 = (int)((blockIdx.x + ((blockIdx.x >> 8) << 4)) & 63u);

  // ---- A fragments (X rows scaled by -4096), fp16, register-resident ----
  half8 ax[2][2];
#pragma unroll
  for (int rt = 0; rt < 2; ++rt) {
#pragma unroll
    for (int kk = 0; kk < 2; ++kk) {
      const float* xr = x + (brow + wrow + rt * 16 + l15) * NSVQ_D + kk * 32 + lg * 8;
      float4 v0 = *(const float4*)xr;
      float4 v1 = *(const float4*)(xr + 4);
      float f[8] = {v0.x, v0.y, v0.z, v0.w, v1.x, v1.y, v1.z, v1.w};
      half8 h;
#pragma unroll
      for (int j = 0; j < 8; ++j) h[j] = (_Float16)(f[j] * -4096.f);
      ax[rt][kk] = h;
    }
  }

  uint u1[8], u2[8];
#pragma unroll
  for (int i = 0; i < 8; ++i) { u1[i] = 0xFFFFFFFFu; u2[i] = 0xFFFFFFFFu; }

  const int lbase = lane * 8;              // ushort offset within a 64-entry group

  auto LOAD = [&](half8& h0, half8& h1, float& cn, int c) {
    int nb = c * 1024 + lbase;
    h0 = *(const half8*)(cbf + nb);
    h1 = *(const half8*)(cbf + nb + 512);
    cn = cn2k[(c << 4) + l15];
  };
  auto COMPUTE = [&](half8 h0, half8 h1, float cc, int ct) {
    const uint kidx = (uint)((ct << 4) + l15);
#pragma unroll
    for (int rt = 0; rt < 2; ++rt) {
      f32x4 a = {cc, cc, cc, cc};
      a = __builtin_amdgcn_mfma_f32_16x16x32_f16(ax[rt][0], h0, a, 0, 0, 0);
      a = __builtin_amdgcn_mfma_f32_16x16x32_f16(ax[rt][1], h1, a, 0, 0, 0);
#pragma unroll
      for (int j = 0; j < 4; ++j) {
        // positive float -> raw bits monotone; one v_and_or packs score|index
        uint m = (__float_as_uint(a[j]) & 0xFFFFFC00u) | kidx;
        int slot = rt * 4 + j;
        uint mm;  // u2' = median(u1, u2, m)  (valid since u1 <= u2 invariant)
        asm("v_med3_u32 %0, %1, %2, %3" : "=v"(mm)
            : "v"(u1[slot]), "v"(u2[slot]), "v"(m));
        u2[slot] = mm;
        u1[slot] = min(u1[slot], m);
      }
    }
  };

  half8 Ah0, Ah1, Bh0, Bh1;
  float cnA, cnB;
  LOAD(Ah0, Ah1, cnA, ct0);
  LOAD(Bh0, Bh1, cnB, (ct0 + 1) & 63);

  for (int p = 0; p < 64; p += 2) {
    COMPUTE(Ah0, Ah1, cnA, (p + ct0) & 63);
    LOAD(Ah0, Ah1, cnA, (p + 2 + ct0) & 63);   // tail wraps: dead values, valid addrs
    COMPUTE(Bh0, Bh1, cnB, (p + 1 + ct0) & 63);
    LOAD(Bh0, Bh1, cnB, (p + 3 + ct0) & 63);
  }

  // ---- cross-lane top-2 merge over the 16 code-lanes; write packed best ----
#pragma unroll
  for (int rt = 0; rt < 2; ++rt) {
#pragma unroll
    for (int j = 0; j < 4; ++j) {
      int slot = rt * 4 + j;
      uint a1 = u1[slot], a2 = u2[slot];
#pragma unroll
      for (int off = 1; off < 16; off <<= 1) {
        uint o1 = (uint)__shfl_xor((int)a1, off);
        uint o2 = (uint)__shfl_xor((int)a2, off);
        a2 = min(min(a2, o2), max(a1, o1));
        a1 = min(a1, o1);
      }
      if (l15 == 0) {
        uint fl = ((a2 >> 10) - (a1 >> 10) < THR_Q) ? 0x80000000u : 0u;
        best[brow + wrow + rt * 16 + lg * 4 + j] =
            fl | ((a2 & 1023u) << 10) | (a1 & 1023u);
      }
    }
  }
}

// ---------------- cleanup: per-thread top-2 exact check + counts histogram ----------------
__global__ __launch_bounds__(256)
void nsvq_cleanup(const float* __restrict__ x,
                  const float* __restrict__ cb,
                  const float* __restrict__ cn2k,
                  uint* __restrict__ best,
                  int* __restrict__ counts) {
  __shared__ int hist[1024];
#pragma unroll
  for (int i = threadIdx.x; i < 1024; i += 256) hist[i] = 0;
  __syncthreads();

  const long row = (long)blockIdx.x * 256 + threadIdx.x;
  uint p = best[row];
  uint k = p & 1023u;
  if (p & 0x80000000u) {
    uint k2 = (p >> 10) & 1023u;
    const float4* xr = (const float4*)(x + row * NSVQ_D);
    const float4* c1 = (const float4*)(cb + (long)k * NSVQ_D);
    const float4* c2 = (const float4*)(cb + (long)k2 * NSVQ_D);
    float d1 = 0.f, d2 = 0.f;
#pragma unroll
    for (int q = 0; q < 16; ++q) {
      float4 xv = xr[q], a = c1[q], b = c2[q];
      d1 = fmaf(xv.x, a.x, d1); d1 = fmaf(xv.y, a.y, d1);
      d1 = fmaf(xv.z, a.z, d1); d1 = fmaf(xv.w, a.w, d1);
      d2 = fmaf(xv.x, b.x, d2); d2 = fmaf(xv.y, b.y, d2);
      d2 = fmaf(xv.z, b.z, d2); d2 = fmaf(xv.w, b.w, d2);
    }
    float s1 = fmaf(-4096.f, d1, cn2k[k]);   // 2048*score, exact fp32 dot
    float s2 = fmaf(-4096.f, d2, cn2k[k2]);
    if (s2 < s1 || (s2 == s1 && k2 < k)) k = k2;
    best[row] = k;                            // clean entry for epilogue
  }
  atomicAdd(&hist[k], 1);
  __syncthreads();
  for (int i = threadIdx.x; i < 1024; i += 256) {
    int v = hist[i];
    if (v) atomicAdd(&counts[i], v);
  }
}

// ---------------- epilogue: noise-substitution quantization ----------------
__global__ __launch_bounds__(256)
void nsvq_epilogue_kernel(const float* __restrict__ x,
                          const float* __restrict__ cb,
                          const float* __restrict__ rv,
                          const uint* __restrict__ best,
                          float* __restrict__ out) {
  const int tid = threadIdx.x;
  const long row = (long)blockIdx.x * 16 + (tid >> 4);
  const int l = tid & 15;
  const int k = (int)(best[row] & 1023u);

  float4 xv = ((const float4*)(x + row * NSVQ_D))[l];
  float4 cv = ((const float4*)(cb + (long)k * NSVQ_D))[l];
  float4 rr = ((const float4*)(rv + row * NSVQ_D))[l];

  float dx = xv.x - cv.x, dy = xv.y - cv.y, dz = xv.z - cv.z, dw = xv.w - cv.w;
  float dres = dx * dx + dy * dy + dz * dz + dw * dw;
  float drnd = rr.x * rr.x + rr.y * rr.y + rr.z * rr.z + rr.w * rr.w;
#pragma unroll
  for (int off = 1; off < 16; off <<= 1) {
    dres += __shfl_xor(dres, off, 64);
    drnd += __shfl_xor(drnd, off, 64);
  }
  float scale = sqrtf(dres) / (sqrtf(drnd) + 1e-12f);

  float4 o;
  o.x = xv.x + scale * rr.x;
  o.y = xv.y + scale * rr.y;
  o.z = xv.z + scale * rr.z;
  o.w = xv.w + scale * rr.w;
  ((float4*)(out + row * NSVQ_D))[l] = o;
}

// ---------------- perplexity + counts output ----------------
__global__ void nsvq_perp_kernel(const int* __restrict__ counts,
                                 float* __restrict__ out_tail,  // [0]=perp, [1..K]=counts
                                 float invN, int K) {
  int t = threadIdx.x;
  float v = 0.f;
  if (t < K) {
    int c = counts[t];
    out_tail[1 + t] = (float)c;
    float p = (float)c * invN;
    v = p * logf(p + 1e-12f);
  }
#pragma unroll
  for (int off = 1; off < 64; off <<= 1) v += __shfl_xor(v, off, 64);
  __shared__ float red[16];
  int wid = t >> 6;
  if ((t & 63) == 0) red[wid] = v;
  __syncthreads();
  if (t == 0) {
    float s = 0.f;
    int nw = (blockDim.x + 63) / 64;
    for (int w = 0; w < nw; ++w) s += red[w];
    out_tail[0] = expf(-s);
  }
}

extern "C" void kernel_launch(void* const* d_in, const int* in_sizes, int n_in,
                              void* d_out, int out_size, void* d_ws, size_t ws_size,
                              hipStream_t stream) {
  const float* x  = (const float*)d_in[0];
  const float* cb = (const float*)d_in[1];
  const float* rv = (const float*)d_in[2];
  float* out = (float*)d_out;

  const int D = NSVQ_D;
  const int N = in_sizes[0] / D;  // 131072
  const int K = in_sizes[1] / D;  // 1024

  float*  cn2k   = (float*)d_ws;
  int*    counts = (int*)((char*)d_ws + 4096);
  uint*   best   = (uint*)((char*)d_ws + 8192);
  ushort* cbf    = (ushort*)((char*)d_ws + 532480);

  nsvq_prep<<<(K + 255) / 256, 256, 0, stream>>>(cb, cbf, cn2k, counts, K);
  nsvq_argmin_mfma<<<N / ABN, 256, 0, stream>>>(x, cbf, cn2k, best);
  nsvq_cleanup<<<N / 256, 256, 0, stream>>>(x, cb, cn2k, best, counts);
  nsvq_epilogue_kernel<<<N / 16, 256, 0, stream>>>(x, cb, rv, best, out);
  nsvq_perp_kernel<<<1, 1024, 0, stream>>>(counts, out + (size_t)N * D, 1.0f / (float)N, K);
}

// Round 20
// 64.238 us; speedup vs baseline: 1.1580x; 1.1580x over previous
//
#include <hip/hip_runtime.h>
#include <math.h>

// NSVQ: N=131072 rows, D=64, K=1024 codes (fp32).
// out (flat f32): [0,N*D) quantized; [N*D] perplexity; [N*D+1,+K) counts.
// ws layout:
//   [0,4096)         cn2k   f32[K]     2048*(||c||^2 + 512)
//   [4096,8192)      counts int[K]
//   [8192,139264)    cbf    fp16[K*64] codebook, MFMA-fragment order
// fragment order: entry (16B) index = ct*128 + kk*64 + lg*16 + l15
//   holds code (ct*16+l15), dims [kk*32+lg*8, +8)  -> wave load is coalesced 1KB

#define NSVQ_D 64
#define ABN 128      // rows per block (256 thr, 4 waves x 32 rows -> grid 1024, 4 blk/CU)
#define THR_Q 12u    // flag threshold in packed quanta (worst quantum 0.03125 raw @ e=19)
                     // certifies gap >= 0.375 raw > 2*fp16_err(0.12) + quantum

typedef __attribute__((ext_vector_type(8))) _Float16 half8;
typedef __attribute__((ext_vector_type(4))) float f32x4;

// ---------------- prep: codebook norms + fp16 fragment-order plane + zero counts ----------------
__global__ __launch_bounds__(256)
void nsvq_prep(const float* __restrict__ cb,
               ushort* __restrict__ cbf,
               float* __restrict__ cn2k, int* __restrict__ counts, int K) {
  if (blockIdx.x == 0) ((int4*)counts)[threadIdx.x] = make_int4(0, 0, 0, 0);
  int r = blockIdx.x * 256 + threadIdx.x;  // one code per thread
  if (r >= K) return;
  const float* row = cb + (long)r * NSVQ_D;
  float nrm = 0.f;
#pragma unroll
  for (int j = 0; j < 8; ++j) {            // dim block j = dims 8j..8j+7
    float4 v0 = *(const float4*)(row + j * 8);
    float4 v1 = *(const float4*)(row + j * 8 + 4);
    float f[8] = {v0.x, v0.y, v0.z, v0.w, v1.x, v1.y, v1.z, v1.w};
    half8 hv;
#pragma unroll
    for (int e = 0; e < 8; ++e) {
      nrm = fmaf(f[e], f[e], nrm);
      hv[e] = (_Float16)f[e];
    }
    // fragment-order entry: ct*128 + kk*64 + lg*16 + l15
    int blk = (r >> 4) * 128 + (j >> 2) * 64 + (j & 3) * 16 + (r & 15);
    *(half8*)(cbf + blk * 8) = hv;
  }
  cn2k[r] = 2048.f * (nrm + 512.f);        // acc-init constant; scores in (0.78M, 1.72M)
}

// ---------------- fused: MFMA argmin + exact recheck + quantize + counts ----------------
__global__ __launch_bounds__(256, 4)
void nsvq_fused(const float* __restrict__ x,
                const ushort* __restrict__ cbf,
                const float* __restrict__ cn2k,
                const float* __restrict__ cb,
                const float* __restrict__ rv,
                int* __restrict__ counts,
                float* __restrict__ out) {
  __shared__ uint bestLds[ABN];            // packed top-2 per row
  __shared__ int hist[1024];
  ((int4*)hist)[threadIdx.x] = make_int4(0, 0, 0, 0);

  const int tid = threadIdx.x;
  const int lane = tid & 63;
  const int wid = tid >> 6;                // 0..3, each wave owns 32 rows
  const int l15 = lane & 15;
  const int lg = lane >> 4;                // 0..3
  const long brow = (long)blockIdx.x * ABN;
  const int wrow = wid * 32;

  // ---- A fragments (X rows scaled by -4096), fp16, register-resident ----
  half8 ax[2][2];
#pragma unroll
  for (int rt = 0; rt < 2; ++rt) {
#pragma unroll
    for (int kk = 0; kk < 2; ++kk) {
      const float* xr = x + (brow + wrow + rt * 16 + l15) * NSVQ_D + kk * 32 + lg * 8;
      float4 v0 = *(const float4*)xr;
      float4 v1 = *(const float4*)(xr + 4);
      float f[8] = {v0.x, v0.y, v0.z, v0.w, v1.x, v1.y, v1.z, v1.w};
      half8 h;
#pragma unroll
      for (int j = 0; j < 8; ++j) h[j] = (_Float16)(f[j] * -4096.f);
      ax[rt][kk] = h;
    }
  }

  uint u1[8], u2[8];
#pragma unroll
  for (int i = 0; i < 8; ++i) { u1[i] = 0xFFFFFFFFu; u2[i] = 0xFFFFFFFFu; }

  const int lbase = lane * 8;              // ushort offset within a 64-entry group

  auto LOAD = [&](half8& h0, half8& h1, float& cn, int c) {
    int nb = c * 1024 + lbase;
    h0 = *(const half8*)(cbf + nb);
    h1 = *(const half8*)(cbf + nb + 512);
    cn = cn2k[(c << 4) + l15];
  };
  auto COMPUTE = [&](half8 h0, half8 h1, float cc, int ct) {
    const uint kidx = (uint)((ct << 4) + l15);
#pragma unroll
    for (int rt = 0; rt < 2; ++rt) {
      f32x4 a = {cc, cc, cc, cc};
      a = __builtin_amdgcn_mfma_f32_16x16x32_f16(ax[rt][0], h0, a, 0, 0, 0);
      a = __builtin_amdgcn_mfma_f32_16x16x32_f16(ax[rt][1], h1, a, 0, 0, 0);
#pragma unroll
      for (int j = 0; j < 4; ++j) {
        // positive float -> raw bits monotone; one v_and_or packs score|index
        uint m = (__float_as_uint(a[j]) & 0xFFFFFC00u) | kidx;
        int slot = rt * 4 + j;
        uint mm;  // u2' = median(u1, u2, m)  (valid since u1 <= u2 invariant)
        asm("v_med3_u32 %0, %1, %2, %3" : "=v"(mm)
            : "v"(u1[slot]), "v"(u2[slot]), "v"(m));
        u2[slot] = mm;
        u1[slot] = min(u1[slot], m);
      }
    }
  };

  half8 Ah0, Ah1, Bh0, Bh1;
  float cnA, cnB;
  LOAD(Ah0, Ah1, cnA, 0);
  LOAD(Bh0, Bh1, cnB, 1);

  for (int ct = 0; ct < 64; ct += 2) {
    COMPUTE(Ah0, Ah1, cnA, ct);
    LOAD(Ah0, Ah1, cnA, (ct + 2) & 63);    // tail wraps: dead values, valid addrs
    COMPUTE(Bh0, Bh1, cnB, ct + 1);
    LOAD(Bh0, Bh1, cnB, (ct + 3) & 63);
  }

  // ---- cross-lane top-2 merge over the 16 code-lanes; deposit packed best in LDS ----
#pragma unroll
  for (int rt = 0; rt < 2; ++rt) {
#pragma unroll
    for (int j = 0; j < 4; ++j) {
      int slot = rt * 4 + j;
      uint a1 = u1[slot], a2 = u2[slot];
#pragma unroll
      for (int off = 1; off < 16; off <<= 1) {
        uint o1 = (uint)__shfl_xor((int)a1, off);
        uint o2 = (uint)__shfl_xor((int)a2, off);
        a2 = min(min(a2, o2), max(a1, o1));
        a1 = min(a1, o1);
      }
      if (l15 == 0) {
        uint fl = ((a2 >> 10) - (a1 >> 10) < THR_Q) ? 0x80000000u : 0u;
        bestLds[wrow + rt * 16 + lg * 4 + j] =
            fl | ((a2 & 1023u) << 10) | (a1 & 1023u);
      }
    }
  }
  __syncthreads();

  // ---- fused tail: 16 lanes/row x 8 passes — exact recheck + quantize + LDS hist ----
  const int l = tid & 15;
  const int rbase = tid >> 4;              // 0..15
#pragma unroll
  for (int pass = 0; pass < 8; ++pass) {
    const int rloc = pass * 16 + rbase;    // local row 0..127
    const long row = brow + rloc;
    uint p = bestLds[rloc];
    uint k = p & 1023u;
    float4 xv = ((const float4*)(x + row * NSVQ_D))[l];

    if (p & 0x80000000u) {                 // near-tie: exact fp32 top-2 check
      uint k2 = (p >> 10) & 1023u;
      float4 a = ((const float4*)(cb + (long)k * NSVQ_D))[l];
      float4 b = ((const float4*)(cb + (long)k2 * NSVQ_D))[l];
      float d1 = xv.x * a.x + xv.y * a.y + xv.z * a.z + xv.w * a.w;
      float d2 = xv.x * b.x + xv.y * b.y + xv.z * b.z + xv.w * b.w;
#pragma unroll
      for (int off = 1; off < 16; off <<= 1) {
        d1 += __shfl_xor(d1, off, 64);
        d2 += __shfl_xor(d2, off, 64);
      }
      float s1 = fmaf(-4096.f, d1, cn2k[k]);   // 2048*score, exact fp32 dot
      float s2 = fmaf(-4096.f, d2, cn2k[k2]);
      if (s2 < s1 || (s2 == s1 && k2 < k)) k = k2;
    }

    float4 cv = ((const float4*)(cb + (long)k * NSVQ_D))[l];
    float4 rr = ((const float4*)(rv + row * NSVQ_D))[l];
    float dx = xv.x - cv.x, dy = xv.y - cv.y, dz = xv.z - cv.z, dw = xv.w - cv.w;
    float dres = dx * dx + dy * dy + dz * dz + dw * dw;
    float drnd = rr.x * rr.x + rr.y * rr.y + rr.z * rr.z + rr.w * rr.w;
#pragma unroll
    for (int off = 1; off < 16; off <<= 1) {
      dres += __shfl_xor(dres, off, 64);
      drnd += __shfl_xor(drnd, off, 64);
    }
    float scale = sqrtf(dres) / (sqrtf(drnd) + 1e-12f);

    float4 o;
    o.x = xv.x + scale * rr.x;
    o.y = xv.y + scale * rr.y;
    o.z = xv.z + scale * rr.z;
    o.w = xv.w + scale * rr.w;
    ((float4*)(out + row * NSVQ_D))[l] = o;

    if (l == 0) atomicAdd(&hist[k], 1);
  }

  // ---- merge block histogram into global counts (sparse) ----
  __syncthreads();
  int v0 = hist[tid];
  int v1 = hist[tid + 256];
  int v2 = hist[tid + 512];
  int v3 = hist[tid + 768];
  if (v0) atomicAdd(&counts[tid], v0);
  if (v1) atomicAdd(&counts[tid + 256], v1);
  if (v2) atomicAdd(&counts[tid + 512], v2);
  if (v3) atomicAdd(&counts[tid + 768], v3);
}

// ---------------- perplexity + counts output ----------------
__global__ void nsvq_perp_kernel(const int* __restrict__ counts,
                                 float* __restrict__ out_tail,  // [0]=perp, [1..K]=counts
                                 float invN, int K) {
  int t = threadIdx.x;
  float v = 0.f;
  if (t < K) {
    int c = counts[t];
    out_tail[1 + t] = (float)c;
    float p = (float)c * invN;
    v = p * logf(p + 1e-12f);
  }
#pragma unroll
  for (int off = 1; off < 64; off <<= 1) v += __shfl_xor(v, off, 64);
  __shared__ float red[16];
  int wid = t >> 6;
  if ((t & 63) == 0) red[wid] = v;
  __syncthreads();
  if (t == 0) {
    float s = 0.f;
    int nw = (blockDim.x + 63) / 64;
    for (int w = 0; w < nw; ++w) s += red[w];
    out_tail[0] = expf(-s);
  }
}

extern "C" void kernel_launch(void* const* d_in, const int* in_sizes, int n_in,
                              void* d_out, int out_size, void* d_ws, size_t ws_size,
                              hipStream_t stream) {
  const float* x  = (const float*)d_in[0];
  const float* cb = (const float*)d_in[1];
  const float* rv = (const float*)d_in[2];
  float* out = (float*)d_out;

  const int D = NSVQ_D;
  const int N = in_sizes[0] / D;  // 131072
  const int K = in_sizes[1] / D;  // 1024

  float*  cn2k   = (float*)d_ws;
  int*    counts = (int*)((char*)d_ws + 4096);
  ushort* cbf    = (ushort*)((char*)d_ws + 8192);

  nsvq_prep<<<(K + 255) / 256, 256, 0, stream>>>(cb, cbf, cn2k, counts, K);
  nsvq_fused<<<N / ABN, 256, 0, stream>>>(x, cbf, cn2k, cb, rv, counts, out);
  nsvq_perp_kernel<<<1, 1024, 0, stream>>>(counts, out + (size_t)N * D, 1.0f / (float)N, K);
}

// Round 21
// 62.729 us; speedup vs baseline: 1.1859x; 1.0240x over previous
//
#include <hip/hip_runtime.h>
#include <math.h>

// NSVQ: N=131072 rows, D=64, K=1024 codes (fp32).
// out (flat f32): [0,N*D) quantized; [N*D] perplexity; [N*D+1,+K) counts.
// ws layout:
//   [0,4096)         cn2k   f32[K]     2048*(||c||^2 + 512)
//   [4096,8192)      counts int[K]
//   [8192,139264)    cbf    fp16[K*64] codebook, 32x32-MFMA fragment order
// fragment order (16B entry): idx = g*256 + ks*64 + lane, lane = (code&31) + 32*(dimblk&1)
//   holds code (g*32 + (lane&31)), dims ks*16 + (lane>>5)*8 + [0..8)

#define NSVQ_D 64
#define ABN 128      // rows per block (256 thr, 4 waves x 32 rows -> grid 1024)
#define THR_Q 12u    // flag threshold in packed quanta (worst quantum 0.03125 raw @ e=19)
                     // certifies gap >= 0.375 raw > 2*fp16_err(0.12) + quantum

typedef __attribute__((ext_vector_type(8))) _Float16 half8;
typedef __attribute__((ext_vector_type(16))) float f32x16;

// ---------------- prep: codebook norms + fp16 32x32-fragment plane + zero counts ----------------
__global__ __launch_bounds__(256)
void nsvq_prep(const float* __restrict__ cb,
               ushort* __restrict__ cbf,
               float* __restrict__ cn2k, int* __restrict__ counts, int K) {
  if (blockIdx.x == 0) ((int4*)counts)[threadIdx.x] = make_int4(0, 0, 0, 0);
  int r = blockIdx.x * 256 + threadIdx.x;  // one code per thread
  if (r >= K) return;
  const float* row = cb + (long)r * NSVQ_D;
  float nrm = 0.f;
#pragma unroll
  for (int j = 0; j < 8; ++j) {            // dim block j = dims 8j..8j+7
    float4 v0 = *(const float4*)(row + j * 8);
    float4 v1 = *(const float4*)(row + j * 8 + 4);
    float f[8] = {v0.x, v0.y, v0.z, v0.w, v1.x, v1.y, v1.z, v1.w};
    half8 hv;
#pragma unroll
    for (int e = 0; e < 8; ++e) {
      nrm = fmaf(f[e], f[e], nrm);
      hv[e] = (_Float16)f[e];
    }
    // 32x32 fragment order: entry = (r>>5)*256 + (j>>1)*64 + (j&1)*32 + (r&31)
    int blk = (r >> 5) * 256 + (j >> 1) * 64 + (j & 1) * 32 + (r & 31);
    *(half8*)(cbf + blk * 8) = hv;
  }
  cn2k[r] = 2048.f * (nrm + 512.f);        // acc-init constant; scores in (0.78M, 1.72M)
}

// ---------------- fused: 32x32x16 MFMA argmin + exact recheck + quantize + counts ----------------
__global__ __launch_bounds__(256, 2)
void nsvq_fused(const float* __restrict__ x,
                const ushort* __restrict__ cbf,
                const float* __restrict__ cn2k,
                const float* __restrict__ cb,
                const float* __restrict__ rv,
                int* __restrict__ counts,
                float* __restrict__ out) {
  __shared__ uint bestLds[ABN];            // packed top-2 per row
  __shared__ int hist[1024];
  ((int4*)hist)[threadIdx.x] = make_int4(0, 0, 0, 0);

  const int tid = threadIdx.x;
  const int lane = tid & 63;
  const int wid = tid >> 6;                // 0..3, each wave owns 32 rows
  const int l31 = lane & 31;               // code-in-group / A-row
  const int lh = lane >> 5;                // k-half
  const long brow = (long)blockIdx.x * ABN;
  const int wrow = wid * 32;

  // ---- A fragments: 32 rows x 64 dims, 4 k-slices of 16; lane holds row l31,
  //      dims ks*16 + lh*8 + [0..8). Scaled by -4096 (folds -2*2048). ----
  half8 ax[4];
#pragma unroll
  for (int ks = 0; ks < 4; ++ks) {
    const float* xr = x + (brow + wrow + l31) * NSVQ_D + ks * 16 + lh * 8;
    float4 v0 = *(const float4*)xr;
    float4 v1 = *(const float4*)(xr + 4);
    float f[8] = {v0.x, v0.y, v0.z, v0.w, v1.x, v1.y, v1.z, v1.w};
    half8 h;
#pragma unroll
    for (int j = 0; j < 8; ++j) h[j] = (_Float16)(f[j] * -4096.f);
    ax[ks] = h;
  }

  uint u1[16], u2[16];
#pragma unroll
  for (int i = 0; i < 16; ++i) { u1[i] = 0xFFFFFFFFu; u2[i] = 0xFFFFFFFFu; }

  auto LOAD = [&](half8 (&B)[4], float& cn, int g) {
    const ushort* p = cbf + (g * 256 + lane) * 8;
#pragma unroll
    for (int ks = 0; ks < 4; ++ks) B[ks] = *(const half8*)(p + ks * 512);
    cn = cn2k[g * 32 + l31];
  };
  auto COMPUTE = [&](const half8 (&B)[4], float cc, int g) {
    const uint kidx = (uint)(g * 32 + l31);
    f32x16 a = {cc, cc, cc, cc, cc, cc, cc, cc, cc, cc, cc, cc, cc, cc, cc, cc};
    a = __builtin_amdgcn_mfma_f32_32x32x16_f16(ax[0], B[0], a, 0, 0, 0);
    a = __builtin_amdgcn_mfma_f32_32x32x16_f16(ax[1], B[1], a, 0, 0, 0);
    a = __builtin_amdgcn_mfma_f32_32x32x16_f16(ax[2], B[2], a, 0, 0, 0);
    a = __builtin_amdgcn_mfma_f32_32x32x16_f16(ax[3], B[3], a, 0, 0, 0);
#pragma unroll
    for (int r = 0; r < 16; ++r) {
      // positive float -> raw bits monotone; one v_and_or packs score|index
      uint m = (__float_as_uint(a[r]) & 0xFFFFFC00u) | kidx;
      uint mm;  // u2' = median(u1, u2, m)  (valid since u1 <= u2 invariant)
      asm("v_med3_u32 %0, %1, %2, %3" : "=v"(mm)
          : "v"(u1[r]), "v"(u2[r]), "v"(m));
      u2[r] = mm;
      u1[r] = min(u1[r], m);
    }
  };

  half8 BA[4], BB[4];
  float cnA, cnB;
  LOAD(BA, cnA, 0);
  LOAD(BB, cnB, 1);

  for (int g = 0; g < 32; g += 2) {        // 32 groups x 32 codes
    COMPUTE(BA, cnA, g);
    LOAD(BA, cnA, (g + 2) & 31);           // tail wraps: dead values, valid addrs
    COMPUTE(BB, cnB, g + 1);
    LOAD(BB, cnB, (g + 3) & 31);
  }

  // ---- cross-lane top-2 merge over the 32 code-lanes (within k-half); deposit in LDS ----
#pragma unroll
  for (int r = 0; r < 16; ++r) {
    uint a1 = u1[r], a2 = u2[r];
#pragma unroll
    for (int off = 1; off < 32; off <<= 1) {   // stays within 32-lane half
      uint o1 = (uint)__shfl_xor((int)a1, off);
      uint o2 = (uint)__shfl_xor((int)a2, off);
      a2 = min(min(a2, o2), max(a1, o1));
      a1 = min(a1, o1);
    }
    if (l31 == 0) {
      // C/D row mapping: row = (r&3) + 8*(r>>2) + 4*lh  (verified m74/m101)
      int rowloc = (r & 3) + 8 * (r >> 2) + 4 * lh;
      uint fl = ((a2 >> 10) - (a1 >> 10) < THR_Q) ? 0x80000000u : 0u;
      bestLds[wrow + rowloc] = fl | ((a2 & 1023u) << 10) | (a1 & 1023u);
    }
  }
  __syncthreads();

  // ---- fused tail: 16 lanes/row x 8 passes — exact recheck + quantize + LDS hist ----
  const int l = tid & 15;
  const int rbase = tid >> 4;              // 0..15
#pragma unroll
  for (int pass = 0; pass < 8; ++pass) {
    const int rloc = pass * 16 + rbase;    // local row 0..127
    const long row = brow + rloc;
    uint p = bestLds[rloc];
    uint k = p & 1023u;
    float4 xv = ((const float4*)(x + row * NSVQ_D))[l];

    if (p & 0x80000000u) {                 // near-tie: exact fp32 top-2 check
      uint k2 = (p >> 10) & 1023u;
      float4 a = ((const float4*)(cb + (long)k * NSVQ_D))[l];
      float4 b = ((const float4*)(cb + (long)k2 * NSVQ_D))[l];
      float d1 = xv.x * a.x + xv.y * a.y + xv.z * a.z + xv.w * a.w;
      float d2 = xv.x * b.x + xv.y * b.y + xv.z * b.z + xv.w * b.w;
#pragma unroll
      for (int off = 1; off < 16; off <<= 1) {
        d1 += __shfl_xor(d1, off, 64);
        d2 += __shfl_xor(d2, off, 64);
      }
      float s1 = fmaf(-4096.f, d1, cn2k[k]);   // 2048*score, exact fp32 dot
      float s2 = fmaf(-4096.f, d2, cn2k[k2]);
      if (s2 < s1 || (s2 == s1 && k2 < k)) k = k2;
    }

    float4 cv = ((const float4*)(cb + (long)k * NSVQ_D))[l];
    float4 rr = ((const float4*)(rv + row * NSVQ_D))[l];
    float dx = xv.x - cv.x, dy = xv.y - cv.y, dz = xv.z - cv.z, dw = xv.w - cv.w;
    float dres = dx * dx + dy * dy + dz * dz + dw * dw;
    float drnd = rr.x * rr.x + rr.y * rr.y + rr.z * rr.z + rr.w * rr.w;
#pragma unroll
    for (int off = 1; off < 16; off <<= 1) {
      dres += __shfl_xor(dres, off, 64);
      drnd += __shfl_xor(drnd, off, 64);
    }
    float scale = sqrtf(dres) / (sqrtf(drnd) + 1e-12f);

    float4 o;
    o.x = xv.x + scale * rr.x;
    o.y = xv.y + scale * rr.y;
    o.z = xv.z + scale * rr.z;
    o.w = xv.w + scale * rr.w;
    ((float4*)(out + row * NSVQ_D))[l] = o;

    if (l == 0) atomicAdd(&hist[k], 1);
  }

  // ---- merge block histogram into global counts (sparse) ----
  __syncthreads();
  int v0 = hist[tid];
  int v1 = hist[tid + 256];
  int v2 = hist[tid + 512];
  int v3 = hist[tid + 768];
  if (v0) atomicAdd(&counts[tid], v0);
  if (v1) atomicAdd(&counts[tid + 256], v1);
  if (v2) atomicAdd(&counts[tid + 512], v2);
  if (v3) atomicAdd(&counts[tid + 768], v3);
}

// ---------------- perplexity + counts output ----------------
__global__ void nsvq_perp_kernel(const int* __restrict__ counts,
                                 float* __restrict__ out_tail,  // [0]=perp, [1..K]=counts
                                 float invN, int K) {
  int t = threadIdx.x;
  float v = 0.f;
  if (t < K) {
    int c = counts[t];
    out_tail[1 + t] = (float)c;
    float p = (float)c * invN;
    v = p * logf(p + 1e-12f);
  }
#pragma unroll
  for (int off = 1; off < 64; off <<= 1) v += __shfl_xor(v, off, 64);
  __shared__ float red[16];
  int wid = t >> 6;
  if ((t & 63) == 0) red[wid] = v;
  __syncthreads();
  if (t == 0) {
    float s = 0.f;
    int nw = (blockDim.x + 63) / 64;
    for (int w = 0; w < nw; ++w) s += red[w];
    out_tail[0] = expf(-s);
  }
}

extern "C" void kernel_launch(void* const* d_in, const int* in_sizes, int n_in,
                              void* d_out, int out_size, void* d_ws, size_t ws_size,
                              hipStream_t stream) {
  const float* x  = (const float*)d_in[0];
  const float* cb = (const float*)d_in[1];
  const float* rv = (const float*)d_in[2];
  float* out = (float*)d_out;

  const int D = NSVQ_D;
  const int N = in_sizes[0] / D;  // 131072
  const int K = in_sizes[1] / D;  // 1024

  float*  cn2k   = (float*)d_ws;
  int*    counts = (int*)((char*)d_ws + 4096);
  ushort* cbf    = (ushort*)((char*)d_ws + 8192);

  nsvq_prep<<<(K + 255) / 256, 256, 0, stream>>>(cb, cbf, cn2k, counts, K);
  nsvq_fused<<<N / ABN, 256, 0, stream>>>(x, cbf, cn2k, cb, rv, counts, out);
  nsvq_perp_kernel<<<1, 1024, 0, stream>>>(counts, out + (size_t)N * D, 1.0f / (float)N, K);
}

// Round 22
// 62.082 us; speedup vs baseline: 1.1982x; 1.0104x over previous
//
#include <hip/hip_runtime.h>
#include <math.h>

// NSVQ: N=131072 rows, D=64, K=1024 codes (fp32).
// out (flat f32): [0,N*D) quantized; [N*D] perplexity; [N*D+1,+K) counts.
// ws layout:
//   [0,4096)         cn2k   f32[K]     2048*(||c||^2 + 512)
//   [4096,8192)      counts int[K]
//   [8192,139264)    cbf    fp16[K*64] codebook, 32x32-MFMA fragment order
// fragment order (16B entry): idx = g*256 + ks*64 + lane
//   holds code (g*32 + (lane&31)), dims ks*16 + (lane>>5)*8 + [0..8)

#define NSVQ_D 64
#define ABN 512      // rows per block (1024 thr, 16 waves x 32 rows -> grid 256, 1 blk/CU)
#define THR_Q 12u    // flag threshold in packed quanta (worst quantum 0.03125 raw @ e=19)
                     // certifies gap >= 0.375 raw > 2*fp16_err(0.12) + quantum

typedef __attribute__((ext_vector_type(8))) _Float16 half8;
typedef __attribute__((ext_vector_type(16))) float f32x16;

// ---------------- prep: codebook norms + fp16 32x32-fragment plane + zero counts ----------------
__global__ __launch_bounds__(256)
void nsvq_prep(const float* __restrict__ cb,
               ushort* __restrict__ cbf,
               float* __restrict__ cn2k, int* __restrict__ counts, int K) {
  if (blockIdx.x == 0) ((int4*)counts)[threadIdx.x] = make_int4(0, 0, 0, 0);
  int r = blockIdx.x * 256 + threadIdx.x;  // one code per thread
  if (r >= K) return;
  const float* row = cb + (long)r * NSVQ_D;
  float nrm = 0.f;
#pragma unroll
  for (int j = 0; j < 8; ++j) {            // dim block j = dims 8j..8j+7
    float4 v0 = *(const float4*)(row + j * 8);
    float4 v1 = *(const float4*)(row + j * 8 + 4);
    float f[8] = {v0.x, v0.y, v0.z, v0.w, v1.x, v1.y, v1.z, v1.w};
    half8 hv;
#pragma unroll
    for (int e = 0; e < 8; ++e) {
      nrm = fmaf(f[e], f[e], nrm);
      hv[e] = (_Float16)f[e];
    }
    // 32x32 fragment order: entry = (r>>5)*256 + (j>>1)*64 + (j&1)*32 + (r&31)
    int blk = (r >> 5) * 256 + (j >> 1) * 64 + (j & 1) * 32 + (r & 31);
    *(half8*)(cbf + blk * 8) = hv;
  }
  cn2k[r] = 2048.f * (nrm + 512.f);        // acc-init constant; scores in (0.78M, 1.72M)
}

// ---------------- fused: LDS-resident codebook, 32x32x16 MFMA argmin + recheck + quantize ----------------
__global__ __launch_bounds__(1024, 1)
void nsvq_fused(const float* __restrict__ x,
                const ushort* __restrict__ cbf,
                const float* __restrict__ cn2k,
                const float* __restrict__ cb,
                const float* __restrict__ rv,
                int* __restrict__ counts,
                float* __restrict__ out) {
  __shared__ ushort CS[65536];             // 128 KB: full fp16 codebook, fragment order
  __shared__ float CN[1024];               // 4 KB: cn2k
  __shared__ uint bestLds[ABN];            // 2 KB: packed top-2 per row
  __shared__ int hist[1024];               // 4 KB

  const int tid = threadIdx.x;
  const int lane = tid & 63;
  const int wid = tid >> 6;                // 0..15, each wave owns 32 rows
  const int l31 = lane & 31;               // code-in-group / A-row
  const int lh = lane >> 5;                // k-half
  const long brow = (long)blockIdx.x * ABN;
  const int wrow = wid * 32;

  // ---- stage codebook + cn to LDS (coalesced), zero hist ----
#pragma unroll
  for (int i = 0; i < 8; ++i) {
    int e = i * 1024 + tid;                // 16B entry index, 0..8191
    ((uint4*)CS)[e] = ((const uint4*)cbf)[e];
  }
  CN[tid] = cn2k[tid];
  hist[tid] = 0;

  // ---- A fragments: 32 rows x 64 dims, 4 k-slices; lane = row l31, dims ks*16+lh*8+[0..8)
  //      scaled by -4096 (folds -2*2048) ----
  half8 ax[4];
#pragma unroll
  for (int ks = 0; ks < 4; ++ks) {
    const float* xr = x + (brow + wrow + l31) * NSVQ_D + ks * 16 + lh * 8;
    float4 v0 = *(const float4*)xr;
    float4 v1 = *(const float4*)(xr + 4);
    float f[8] = {v0.x, v0.y, v0.z, v0.w, v1.x, v1.y, v1.z, v1.w};
    half8 h;
#pragma unroll
    for (int j = 0; j < 8; ++j) h[j] = (_Float16)(f[j] * -4096.f);
    ax[ks] = h;
  }

  uint u1[16], u2[16];
#pragma unroll
  for (int i = 0; i < 16; ++i) { u1[i] = 0xFFFFFFFFu; u2[i] = 0xFFFFFFFFu; }

  __syncthreads();                         // codebook resident

  auto LOADL = [&](half8 (&B)[4], float& cn, int g) {
    const ushort* p = CS + (g * 256 + lane) * 8;
#pragma unroll
    for (int ks = 0; ks < 4; ++ks) B[ks] = *(const half8*)(p + ks * 512);
    cn = CN[g * 32 + l31];
  };
  auto COMPUTE = [&](const half8 (&B)[4], float cc, int g) {
    const uint kidx = (uint)(g * 32 + l31);
    f32x16 a = {cc, cc, cc, cc, cc, cc, cc, cc, cc, cc, cc, cc, cc, cc, cc, cc};
    a = __builtin_amdgcn_mfma_f32_32x32x16_f16(ax[0], B[0], a, 0, 0, 0);
    a = __builtin_amdgcn_mfma_f32_32x32x16_f16(ax[1], B[1], a, 0, 0, 0);
    a = __builtin_amdgcn_mfma_f32_32x32x16_f16(ax[2], B[2], a, 0, 0, 0);
    a = __builtin_amdgcn_mfma_f32_32x32x16_f16(ax[3], B[3], a, 0, 0, 0);
#pragma unroll
    for (int r = 0; r < 16; ++r) {
      // positive float -> raw bits monotone; one v_and_or packs score|index
      uint m = (__float_as_uint(a[r]) & 0xFFFFFC00u) | kidx;
      uint mm;  // u2' = median(u1, u2, m)  (valid since u1 <= u2 invariant)
      asm("v_med3_u32 %0, %1, %2, %3" : "=v"(mm)
          : "v"(u1[r]), "v"(u2[r]), "v"(m));
      u2[r] = mm;
      u1[r] = min(u1[r], m);
    }
  };

  half8 BA[4], BB[4];
  float cnA, cnB;
  LOADL(BA, cnA, 0);
  LOADL(BB, cnB, 1);

  for (int g = 0; g < 32; g += 2) {        // 32 groups x 32 codes, LDS-fed
    COMPUTE(BA, cnA, g);
    LOADL(BA, cnA, (g + 2) & 31);          // tail wraps: dead values, valid addrs
    COMPUTE(BB, cnB, g + 1);
    LOADL(BB, cnB, (g + 3) & 31);
  }

  // ---- cross-lane top-2 merge over the 32 code-lanes; deposit packed best in LDS ----
#pragma unroll
  for (int r = 0; r < 16; ++r) {
    uint a1 = u1[r], a2 = u2[r];
#pragma unroll
    for (int off = 1; off < 32; off <<= 1) {   // stays within 32-lane half
      uint o1 = (uint)__shfl_xor((int)a1, off);
      uint o2 = (uint)__shfl_xor((int)a2, off);
      a2 = min(min(a2, o2), max(a1, o1));
      a1 = min(a1, o1);
    }
    if (l31 == 0) {
      // C/D row mapping: row = (r&3) + 8*(r>>2) + 4*lh  (verified m74/m101)
      int rowloc = (r & 3) + 8 * (r >> 2) + 4 * lh;
      uint fl = ((a2 >> 10) - (a1 >> 10) < THR_Q) ? 0x80000000u : 0u;
      bestLds[wrow + rowloc] = fl | ((a2 & 1023u) << 10) | (a1 & 1023u);
    }
  }
  __syncthreads();

  // ---- fused tail: 16 lanes/row, 64 rows/pass x 8 — exact recheck + quantize + hist ----
  const int l = tid & 15;
  const int rbase = tid >> 4;              // 0..63
#pragma unroll
  for (int pass = 0; pass < 8; ++pass) {
    const int rloc = pass * 64 + rbase;    // local row 0..511
    const long row = brow + rloc;
    uint p = bestLds[rloc];
    uint k = p & 1023u;
    float4 xv = ((const float4*)(x + row * NSVQ_D))[l];

    if (p & 0x80000000u) {                 // near-tie: exact fp32 top-2 check
      uint k2 = (p >> 10) & 1023u;
      float4 a = ((const float4*)(cb + (long)k * NSVQ_D))[l];
      float4 b = ((const float4*)(cb + (long)k2 * NSVQ_D))[l];
      float d1 = xv.x * a.x + xv.y * a.y + xv.z * a.z + xv.w * a.w;
      float d2 = xv.x * b.x + xv.y * b.y + xv.z * b.z + xv.w * b.w;
#pragma unroll
      for (int off = 1; off < 16; off <<= 1) {
        d1 += __shfl_xor(d1, off, 64);
        d2 += __shfl_xor(d2, off, 64);
      }
      float s1 = fmaf(-4096.f, d1, cn2k[k]);   // 2048*score, exact fp32 dot
      float s2 = fmaf(-4096.f, d2, cn2k[k2]);
      if (s2 < s1 || (s2 == s1 && k2 < k)) k = k2;
    }

    float4 cv = ((const float4*)(cb + (long)k * NSVQ_D))[l];
    float4 rr = ((const float4*)(rv + row * NSVQ_D))[l];
    float dx = xv.x - cv.x, dy = xv.y - cv.y, dz = xv.z - cv.z, dw = xv.w - cv.w;
    float dres = dx * dx + dy * dy + dz * dz + dw * dw;
    float drnd = rr.x * rr.x + rr.y * rr.y + rr.z * rr.z + rr.w * rr.w;
#pragma unroll
    for (int off = 1; off < 16; off <<= 1) {
      dres += __shfl_xor(dres, off, 64);
      drnd += __shfl_xor(drnd, off, 64);
    }
    float scale = sqrtf(dres) / (sqrtf(drnd) + 1e-12f);

    float4 o;
    o.x = xv.x + scale * rr.x;
    o.y = xv.y + scale * rr.y;
    o.z = xv.z + scale * rr.z;
    o.w = xv.w + scale * rr.w;
    ((float4*)(out + row * NSVQ_D))[l] = o;

    if (l == 0) atomicAdd(&hist[k], 1);
  }

  // ---- merge block histogram into global counts (sparse) ----
  __syncthreads();
  int v = hist[tid];
  if (v) atomicAdd(&counts[tid], v);
}

// ---------------- perplexity + counts output ----------------
__global__ void nsvq_perp_kernel(const int* __restrict__ counts,
                                 float* __restrict__ out_tail,  // [0]=perp, [1..K]=counts
                                 float invN, int K) {
  int t = threadIdx.x;
  float v = 0.f;
  if (t < K) {
    int c = counts[t];
    out_tail[1 + t] = (float)c;
    float p = (float)c * invN;
    v = p * logf(p + 1e-12f);
  }
#pragma unroll
  for (int off = 1; off < 64; off <<= 1) v += __shfl_xor(v, off, 64);
  __shared__ float red[16];
  int wid = t >> 6;
  if ((t & 63) == 0) red[wid] = v;
  __syncthreads();
  if (t == 0) {
    float s = 0.f;
    int nw = (blockDim.x + 63) / 64;
    for (int w = 0; w < nw; ++w) s += red[w];
    out_tail[0] = expf(-s);
  }
}

extern "C" void kernel_launch(void* const* d_in, const int* in_sizes, int n_in,
                              void* d_out, int out_size, void* d_ws, size_t ws_size,
                              hipStream_t stream) {
  const float* x  = (const float*)d_in[0];
  const float* cb = (const float*)d_in[1];
  const float* rv = (const float*)d_in[2];
  float* out = (float*)d_out;

  const int D = NSVQ_D;
  const int N = in_sizes[0] / D;  // 131072
  const int K = in_sizes[1] / D;  // 1024

  float*  cn2k   = (float*)d_ws;
  int*    counts = (int*)((char*)d_ws + 4096);
  ushort* cbf    = (ushort*)((char*)d_ws + 8192);

  nsvq_prep<<<(K + 255) / 256, 256, 0, stream>>>(cb, cbf, cn2k, counts, K);
  nsvq_fused<<<N / ABN, 1024, 0, stream>>>(x, cbf, cn2k, cb, rv, counts, out);
  nsvq_perp_kernel<<<1, 1024, 0, stream>>>(counts, out + (size_t)N * D, 1.0f / (float)N, K);
}